// Round 1
// baseline (3670.728 us; speedup 1.0000x reference)
//
#include <hip/hip_runtime.h>
#include <math.h>

#define BN_ 2
#define CIN 256
#define HH_ 64
#define W2_ 128
#define PP 8192          // H*W2
#define KC_ 32
#define VC_ 256
#define NTOT 16384       // B*P
#define EPS_ 1e-5f

// ---------------- Kernel 0: conv_w (256,1024,3,3) -> wt[d][o][c] ----------------
__global__ __launch_bounds__(256) void transpose_w_kernel(const float* __restrict__ cw,
                                                          float* __restrict__ wt) {
    int j = blockIdx.x * 256 + threadIdx.x;          // 9*256*1024 = 2359296
    if (j >= 9 * 256 * 1024) return;
    int d = j / (256 * 1024);
    int o = (j / 1024) % 256;
    int c = j % 1024;
    wt[j] = cw[o * 9216 + c * 9 + d];
}

// ---------------- Kernel 1: QKV GEMM + BN, windowed output layout ----------------
// out qkv[wi][320][L]; rows 0..31 q (BN), 32..63 k (BN), 64..319 v (+bias)
__global__ __launch_bounds__(256) void qkv_kernel(
    const float* __restrict__ feats,
    const float* __restrict__ qw, const float* __restrict__ qb,
    const float* __restrict__ qg, const float* __restrict__ qbe,
    const float* __restrict__ qm, const float* __restrict__ qv,
    const float* __restrict__ kw, const float* __restrict__ kb,
    const float* __restrict__ kg, const float* __restrict__ kbe,
    const float* __restrict__ km, const float* __restrict__ kvv,
    const float* __restrict__ vw, const float* __restrict__ vb,
    float* __restrict__ qkv, int s)
{
    const int hs = 64 / s, wsz = 64 / s, L = hs * wsz * 2;
    const int t = threadIdx.x;
    const int n0 = blockIdx.x * 64;
    const int r0 = blockIdx.y * 64;

    __shared__ float As[16][68];
    __shared__ float Bs[16][68];
    __shared__ int pmap[64];

    if (t < 64) {
        int n = n0 + t;
        int wi = n / L, l = n % L;
        int i_blk = wi / (s * BN_);
        int j_blk = (wi / BN_) % s;
        int hh = l / (wsz * 2);
        int rem = l % (wsz * 2);
        int ww = rem >> 1, half = rem & 1;
        pmap[t] = (i_blk * hs + hh) * W2_ + half * 64 + j_blk * wsz + ww;
    }
    __syncthreads();

    const int wi = n0 / L;
    const int b  = wi % BN_;
    const int l0 = n0 % L;

    float acc[4][4] = {};
    const int tx = t % 16, ty = t / 16;

    for (int k0 = 0; k0 < 256; k0 += 16) {
        {
            int kk = t % 16, rr = t / 16;
            #pragma unroll
            for (int it = 0; it < 4; ++it) {
                int r = r0 + rr + it * 16;
                const float* wp = (r < 32) ? (qw + r * 256)
                                 : (r < 64) ? (kw + (r - 32) * 256)
                                            : (vw + (r - 64) * 256);
                As[kk][rr + it * 16] = wp[k0 + kk];
            }
        }
        {
            int nn = t % 64, kb_ = t / 64;
            #pragma unroll
            for (int it = 0; it < 4; ++it) {
                int k = kb_ + it * 4;
                Bs[k][nn] = feats[((size_t)b * CIN + k0 + k) * PP + pmap[nn]];
            }
        }
        __syncthreads();
        #pragma unroll
        for (int k = 0; k < 16; ++k) {
            const float4 av = *(const float4*)&As[k][ty * 4];
            const float4 bv = *(const float4*)&Bs[k][tx * 4];
            const float ar[4] = {av.x, av.y, av.z, av.w};
            const float br[4] = {bv.x, bv.y, bv.z, bv.w};
            #pragma unroll
            for (int i = 0; i < 4; ++i)
                #pragma unroll
                for (int j = 0; j < 4; ++j)
                    acc[i][j] = fmaf(ar[i], br[j], acc[i][j]);
        }
        __syncthreads();
    }

    #pragma unroll
    for (int i = 0; i < 4; ++i) {
        int r = r0 + ty * 4 + i;
        float alpha, beta;
        if (r < 32) {
            float sc = qg[r] / sqrtf(qv[r] + EPS_);
            alpha = sc; beta = qb[r] * sc + qbe[r] - qm[r] * sc;
        } else if (r < 64) {
            int u = r - 32;
            float sc = kg[u] / sqrtf(kvv[u] + EPS_);
            alpha = sc; beta = kb[u] * sc + kbe[u] - km[u] * sc;
        } else {
            alpha = 1.f; beta = vb[r - 64];
        }
        float4 o;
        o.x = fmaf(acc[i][0], alpha, beta);
        o.y = fmaf(acc[i][1], alpha, beta);
        o.z = fmaf(acc[i][2], alpha, beta);
        o.w = fmaf(acc[i][3], alpha, beta);
        *(float4*)&qkv[((size_t)wi * 320 + r) * L + l0 + tx * 4] = o;
    }
}

// ---------------- Kernel 2: windowed flash attention ----------------
// grid (L/64, Nw); 256 threads; acc: 8q x 8c per thread
__global__ __launch_bounds__(256) void attn_kernel(
    const float* __restrict__ qkv, float* __restrict__ ctx, int s, int sc_idx)
{
    const int hs = 64 / s, wsz = 64 / s, L = hs * wsz * 2;
    const int t = threadIdx.x;
    const int wi = blockIdx.y;
    const int q0 = blockIdx.x * 64;
    const int b = wi % BN_;

    __shared__ float Qs[64][36];
    __shared__ float Ks[32][36];
    __shared__ float Vs[32][260];
    __shared__ float Ps[64][36];
    __shared__ float row_max[64], row_l[64], row_scale[64];
    __shared__ float pmax[4][64], psum[4][64];
    __shared__ int pmap[64];

    if (t < 64) {
        row_max[t] = -1e30f;
        row_l[t] = 0.f;
        int l = q0 + t;
        int i_blk = wi / (s * BN_), j_blk = (wi / BN_) % s;
        int hh = l / (wsz * 2), rem = l % (wsz * 2);
        pmap[t] = (i_blk * hs + hh) * W2_ + (rem & 1) * 64 + j_blk * wsz + (rem >> 1);
    }
    const float* qbase = qkv + (size_t)wi * 320 * L;
    const float qscale = 0.17677669529663687f;   // 32^-0.5
    {
        int l = t % 64, chb = t / 64;
        #pragma unroll
        for (int it = 0; it < 8; ++it) {
            int ch = chb + it * 4;
            Qs[l][ch] = qbase[(size_t)ch * L + q0 + l] * qscale;
        }
    }
    __syncthreads();

    float acc[8][8] = {};
    const int tx = t % 32, ty = t / 32;
    const int sq = t & 63, w = t >> 6;

    for (int m0 = 0; m0 < L; m0 += 32) {
        {
            int m = t % 32, chb = t / 32;
            #pragma unroll
            for (int it = 0; it < 4; ++it) {
                int ch = chb + it * 8;
                Ks[ch][m] = qbase[(size_t)(32 + ch) * L + m0 + m];
            }
            #pragma unroll
            for (int it = 0; it < 32; ++it) {
                int c = chb + it * 8;
                Vs[m][c] = qbase[(size_t)(64 + c) * L + m0 + m];
            }
        }
        __syncthreads();

        // ---- scores: thread -> (q=sq, m = w*8..w*8+7)
        float sc8[8];
        #pragma unroll
        for (int j = 0; j < 8; ++j) sc8[j] = 0.f;
        #pragma unroll
        for (int c4 = 0; c4 < 8; ++c4) {
            const float4 qv4 = *(const float4*)&Qs[sq][c4 * 4];
            const float qq[4] = {qv4.x, qv4.y, qv4.z, qv4.w};
            #pragma unroll
            for (int u = 0; u < 4; ++u) {
                const float4 k0v = *(const float4*)&Ks[c4 * 4 + u][w * 8];
                const float4 k1v = *(const float4*)&Ks[c4 * 4 + u][w * 8 + 4];
                sc8[0] = fmaf(qq[u], k0v.x, sc8[0]);
                sc8[1] = fmaf(qq[u], k0v.y, sc8[1]);
                sc8[2] = fmaf(qq[u], k0v.z, sc8[2]);
                sc8[3] = fmaf(qq[u], k0v.w, sc8[3]);
                sc8[4] = fmaf(qq[u], k1v.x, sc8[4]);
                sc8[5] = fmaf(qq[u], k1v.y, sc8[5]);
                sc8[6] = fmaf(qq[u], k1v.z, sc8[6]);
                sc8[7] = fmaf(qq[u], k1v.w, sc8[7]);
            }
        }
        float pm = sc8[0];
        #pragma unroll
        for (int j = 1; j < 8; ++j) pm = fmaxf(pm, sc8[j]);
        pmax[w][sq] = pm;
        __syncthreads();

        if (t < 64) {
            float M_old = row_max[t];
            float M = fmaxf(M_old, fmaxf(fmaxf(pmax[0][t], pmax[1][t]),
                                         fmaxf(pmax[2][t], pmax[3][t])));
            row_max[t] = M;
            row_scale[t] = __expf(M_old - M);
        }
        __syncthreads();

        {
            float M = row_max[sq];
            float ps = 0.f;
            #pragma unroll
            for (int j = 0; j < 8; ++j) {
                float p = __expf(sc8[j] - M);
                ps += p;
                Ps[sq][w * 8 + j] = p;
            }
            psum[w][sq] = ps;
        }
        __syncthreads();

        if (t < 64)
            row_l[t] = row_l[t] * row_scale[t] +
                       psum[0][t] + psum[1][t] + psum[2][t] + psum[3][t];

        // ---- PV: thread -> q = ty*8+i, c = tx*4+jj (jj<4) / 128+tx*4+jj-4
        #pragma unroll
        for (int i = 0; i < 8; ++i) {
            float r = row_scale[ty * 8 + i];
            #pragma unroll
            for (int j = 0; j < 8; ++j) acc[i][j] *= r;
        }
        #pragma unroll
        for (int m4 = 0; m4 < 8; ++m4) {
            float4 pv[8];
            #pragma unroll
            for (int i = 0; i < 8; ++i)
                pv[i] = *(const float4*)&Ps[ty * 8 + i][m4 * 4];
            float4 va[4], vb4[4];
            #pragma unroll
            for (int u = 0; u < 4; ++u) {
                va[u]  = *(const float4*)&Vs[m4 * 4 + u][tx * 4];
                vb4[u] = *(const float4*)&Vs[m4 * 4 + u][128 + tx * 4];
            }
            #pragma unroll
            for (int i = 0; i < 8; ++i) {
                const float pr[4] = {pv[i].x, pv[i].y, pv[i].z, pv[i].w};
                #pragma unroll
                for (int u = 0; u < 4; ++u) {
                    acc[i][0] = fmaf(pr[u], va[u].x,  acc[i][0]);
                    acc[i][1] = fmaf(pr[u], va[u].y,  acc[i][1]);
                    acc[i][2] = fmaf(pr[u], va[u].z,  acc[i][2]);
                    acc[i][3] = fmaf(pr[u], va[u].w,  acc[i][3]);
                    acc[i][4] = fmaf(pr[u], vb4[u].x, acc[i][4]);
                    acc[i][5] = fmaf(pr[u], vb4[u].y, acc[i][5]);
                    acc[i][6] = fmaf(pr[u], vb4[u].z, acc[i][6]);
                    acc[i][7] = fmaf(pr[u], vb4[u].w, acc[i][7]);
                }
            }
        }
        __syncthreads();
    }

    // ---- epilogue: divide by l, stage 32-channel slabs, coalesced scatter
    float invl[8];
    #pragma unroll
    for (int i = 0; i < 8; ++i) invl[i] = 1.0f / row_l[ty * 8 + i];

    float* stage = &Ps[0][0];                      // reuse as [32][68]
    float* outbase = ctx + ((size_t)b * 1024 + (size_t)sc_idx * 256) * PP;

    for (int cb = 0; cb < 8; ++cb) {
        int txbase = (cb & 3) * 8;
        bool lower = cb < 4;
        if (tx >= txbase && tx < txbase + 8) {
            #pragma unroll
            for (int i = 0; i < 8; ++i) {
                int q = ty * 8 + i;
                #pragma unroll
                for (int jj = 0; jj < 4; ++jj) {
                    int j = lower ? jj : 4 + jj;
                    int cc = (tx - txbase) * 4 + jj;
                    stage[cc * 68 + q] = acc[i][j] * invl[i];
                }
            }
        }
        __syncthreads();
        {
            int q = t % 64, cc0 = t / 64;
            #pragma unroll
            for (int it = 0; it < 8; ++it) {
                int cc = cc0 + it * 4;
                outbase[(size_t)(cb * 32 + cc) * PP + pmap[q]] = stage[cc * 68 + q];
            }
        }
        __syncthreads();
    }
}

// ---------------- Kernel 3: 3x3 conv as 9 shifted GEMMs + BN + ReLU ----------------
__global__ __launch_bounds__(256) void conv_kernel(
    const float* __restrict__ ctx, const float* __restrict__ wt,
    const float* __restrict__ cbias, const float* __restrict__ cg,
    const float* __restrict__ cbe, const float* __restrict__ cm,
    const float* __restrict__ cv, float* __restrict__ out)
{
    const int t = threadIdx.x;
    const int n0 = blockIdx.x * 64;
    const int o0 = blockIdx.y * 64;
    const int b = n0 / PP;
    const int rem = n0 % PP;
    const int y = rem / W2_;
    const int x0 = rem % W2_;

    __shared__ float As[16][68];
    __shared__ float Bs[16][68];
    float acc[4][4] = {};
    const int tx = t % 16, ty = t / 16;

    for (int d = 0; d < 9; ++d) {
        int dy = d / 3 - 1, dx = d % 3 - 1;
        int yy = y + dy;
        bool yok = (yy >= 0 && yy < HH_);
        const float* wbase = wt + (size_t)d * 256 * 1024 + (size_t)o0 * 1024;
        const float* cbase = ctx + (size_t)b * 1024 * PP + (size_t)yy * W2_;

        for (int c0 = 0; c0 < 1024; c0 += 16) {
            {
                int kk = t % 16, rr = t / 16;
                #pragma unroll
                for (int it = 0; it < 4; ++it) {
                    int r = rr + it * 16;
                    As[kk][r] = wbase[(size_t)r * 1024 + c0 + kk];
                }
            }
            {
                int nn = t % 64, kb_ = t / 64;
                int xx = x0 + nn + dx;
                bool ok = yok && (xx >= 0) && (xx < W2_);
                #pragma unroll
                for (int it = 0; it < 4; ++it) {
                    int k = kb_ + it * 4;
                    Bs[k][nn] = ok ? cbase[(size_t)(c0 + k) * PP + xx] : 0.f;
                }
            }
            __syncthreads();
            #pragma unroll
            for (int k = 0; k < 16; ++k) {
                const float4 av = *(const float4*)&As[k][ty * 4];
                const float4 bv = *(const float4*)&Bs[k][tx * 4];
                const float ar[4] = {av.x, av.y, av.z, av.w};
                const float br[4] = {bv.x, bv.y, bv.z, bv.w};
                #pragma unroll
                for (int i = 0; i < 4; ++i)
                    #pragma unroll
                    for (int j = 0; j < 4; ++j)
                        acc[i][j] = fmaf(ar[i], br[j], acc[i][j]);
            }
            __syncthreads();
        }
    }

    #pragma unroll
    for (int i = 0; i < 4; ++i) {
        int o = o0 + ty * 4 + i;
        float sc = cg[o] / sqrtf(cv[o] + EPS_);
        float sh = cbe[o] - cm[o] * sc;
        float bias = cbias[o];
        float4 v;
        v.x = fmaxf(fmaf(acc[i][0] + bias, sc, sh), 0.f);
        v.y = fmaxf(fmaf(acc[i][1] + bias, sc, sh), 0.f);
        v.z = fmaxf(fmaf(acc[i][2] + bias, sc, sh), 0.f);
        v.w = fmaxf(fmaf(acc[i][3] + bias, sc, sh), 0.f);
        *(float4*)&out[((size_t)b * 256 + o) * PP + rem + tx * 4] = v;
    }
}

// ---------------- host launch ----------------
extern "C" void kernel_launch(void* const* d_in, const int* in_sizes, int n_in,
                              void* d_out, int out_size, void* d_ws, size_t ws_size,
                              hipStream_t stream)
{
    const float* feats  = (const float*)d_in[0];
    const float* q_w    = (const float*)d_in[1];
    const float* q_b    = (const float*)d_in[2];
    const float* q_g    = (const float*)d_in[3];
    const float* q_be   = (const float*)d_in[4];
    const float* q_m    = (const float*)d_in[5];
    const float* q_v    = (const float*)d_in[6];
    const float* k_w    = (const float*)d_in[7];
    const float* k_b    = (const float*)d_in[8];
    const float* k_g    = (const float*)d_in[9];
    const float* k_be   = (const float*)d_in[10];
    const float* k_m    = (const float*)d_in[11];
    const float* k_v    = (const float*)d_in[12];
    const float* v_w    = (const float*)d_in[13];
    const float* v_b    = (const float*)d_in[14];
    const float* conv_w = (const float*)d_in[15];
    const float* conv_b = (const float*)d_in[16];
    const float* c_g    = (const float*)d_in[17];
    const float* c_be   = (const float*)d_in[18];
    const float* c_m    = (const float*)d_in[19];
    const float* c_v    = (const float*)d_in[20];

    float* ws  = (float*)d_ws;
    float* qkv = ws;                       // 320*16384           = 5,242,880 f
    float* ctx = ws + 5242880;             // 2*1024*8192         = 16,777,216 f
    float* wt  = ctx + 16777216;           // 9*256*1024          = 2,359,296 f
    // total workspace: 24,379,392 floats = 97.5 MB

    transpose_w_kernel<<<dim3(9216), dim3(256), 0, stream>>>(conv_w, wt);

    const int sizes[4] = {1, 2, 4, 8};
    for (int si = 0; si < 4; ++si) {
        int s = sizes[si];
        qkv_kernel<<<dim3(256, 5), dim3(256), 0, stream>>>(
            feats,
            q_w + si * 32 * 256, q_b + si * 32, q_g + si * 32, q_be + si * 32,
            q_m + si * 32, q_v + si * 32,
            k_w + si * 32 * 256, k_b + si * 32, k_g + si * 32, k_be + si * 32,
            k_m + si * 32, k_v + si * 32,
            v_w + si * 256 * 256, v_b + si * 256,
            qkv, s);
        int L  = (64 / s) * (64 / s) * 2;
        int Nw = s * s * BN_;
        attn_kernel<<<dim3(L / 64, Nw), dim3(256), 0, stream>>>(qkv, ctx, s, si);
    }

    conv_kernel<<<dim3(256, 4), dim3(256), 0, stream>>>(
        ctx, wt, conv_b, c_g, c_be, c_m, c_v, (float*)d_out);
}

// Round 2
// 1357.076 us; speedup vs baseline: 2.7049x; 2.7049x over previous
//
#include <hip/hip_runtime.h>
#include <math.h>

#define BN_ 2
#define CIN 256
#define HH_ 64
#define W2_ 128
#define PP 8192
#define EPS_ 1e-5f
#define QSCL 0.17677669529663687f

typedef __attribute__((ext_vector_type(4))) float  f32x4;
typedef __attribute__((ext_vector_type(8))) short  short8;
typedef __attribute__((ext_vector_type(4))) short  short4v;
typedef __attribute__((ext_vector_type(8))) __bf16 bf16x8;

static __device__ __forceinline__ short f2bf(float x) {
    unsigned u = __builtin_bit_cast(unsigned, x);
    u = u + 0x7FFFu + ((u >> 16) & 1u);
    return (short)(u >> 16);
}
static __device__ __forceinline__ float bf2f(short s) {
    unsigned u = ((unsigned)(unsigned short)s) << 16;
    return __builtin_bit_cast(float, u);
}
static __device__ __forceinline__ f32x4 mfma16(short8 a, short8 b, f32x4 c) {
    return __builtin_amdgcn_mfma_f32_16x16x32_bf16(
        __builtin_bit_cast(bf16x8, a), __builtin_bit_cast(bf16x8, b), c, 0, 0, 0);
}
// swizzled byte offset for [row][RB bytes] LDS tiles (T2/G4 XOR form)
static __device__ __forceinline__ int swz(int row, int chunk, int RB) {
    return (row * RB + chunk) ^ ((row & 7) << 4);
}

// ---------------- Kernel 0: conv_w (256,1024,3,3) -> wt_hi/lo[d][o][c] ----------------
__global__ __launch_bounds__(256) void wsplit_kernel(const float* __restrict__ cw,
                                                     short* __restrict__ wt_hi,
                                                     short* __restrict__ wt_lo) {
    __shared__ float tile[2304];
    const int o = blockIdx.x, c0 = blockIdx.y * 256, t = threadIdx.x;
    for (int i = t; i < 2304; i += 256) tile[i] = cw[(size_t)o * 9216 + (size_t)c0 * 9 + i];
    __syncthreads();
    #pragma unroll
    for (int d = 0; d < 9; ++d) {
        float v = tile[t * 9 + d];
        short h = f2bf(v);
        size_t off = ((size_t)(d * 256 + o)) * 1024 + c0 + t;
        wt_hi[off] = h;
        wt_lo[off] = f2bf(v - bf2f(h));
    }
}

// ---------------- Kernel 1: QKV GEMM (fp32 VALU) + BN, hi/lo bf16 outputs ----------------
// outputs: qT/kT: [wi][l][32] (c-contig), v: [wi][256][L] (l-contig)
__global__ __launch_bounds__(256) void qkv_kernel(
    const float* __restrict__ feats,
    const float* __restrict__ qw, const float* __restrict__ qb,
    const float* __restrict__ qg, const float* __restrict__ qbe,
    const float* __restrict__ qm, const float* __restrict__ qv,
    const float* __restrict__ kw, const float* __restrict__ kb,
    const float* __restrict__ kg, const float* __restrict__ kbe,
    const float* __restrict__ km, const float* __restrict__ kvv,
    const float* __restrict__ vw, const float* __restrict__ vb,
    short* __restrict__ qT_hi, short* __restrict__ qT_lo,
    short* __restrict__ kT_hi, short* __restrict__ kT_lo,
    short* __restrict__ v_hi,  short* __restrict__ v_lo,
    int s)
{
    const int hs = 64 / s, wsz = 64 / s, L = hs * wsz * 2;
    const int t = threadIdx.x;
    const int n0 = blockIdx.x * 64;
    const int r0 = blockIdx.y * 64;

    __shared__ float As[16][68];
    __shared__ float Bs[16][68];
    __shared__ int pmap[64];

    if (t < 64) {
        int n = n0 + t;
        int wi_ = n / L, lq = n % L;
        int i_blk = wi_ / (s * BN_);
        int j_blk = (wi_ / BN_) % s;
        int hh = lq / (wsz * 2);
        int rem = lq % (wsz * 2);
        pmap[t] = (i_blk * hs + hh) * W2_ + (rem & 1) * 64 + j_blk * wsz + (rem >> 1);
    }
    __syncthreads();

    const int wi = n0 / L;
    const int b  = wi % BN_;
    const int l0 = n0 % L;

    float acc[4][4] = {};
    const int tx = t % 16, ty = t / 16;

    for (int k0 = 0; k0 < 256; k0 += 16) {
        {
            int kk = t % 16, rr = t / 16;
            #pragma unroll
            for (int it = 0; it < 4; ++it) {
                int r = r0 + rr + it * 16;
                const float* wp = (r < 32) ? (qw + r * 256)
                                 : (r < 64) ? (kw + (r - 32) * 256)
                                            : (vw + (r - 64) * 256);
                As[kk][rr + it * 16] = wp[k0 + kk];
            }
        }
        {
            int nn = t % 64, kb_ = t / 64;
            #pragma unroll
            for (int it = 0; it < 4; ++it) {
                int k = kb_ + it * 4;
                Bs[k][nn] = feats[((size_t)b * CIN + k0 + k) * PP + pmap[nn]];
            }
        }
        __syncthreads();
        #pragma unroll
        for (int k = 0; k < 16; ++k) {
            const float4 av = *(const float4*)&As[k][ty * 4];
            const float4 bv = *(const float4*)&Bs[k][tx * 4];
            const float ar[4] = {av.x, av.y, av.z, av.w};
            const float br[4] = {bv.x, bv.y, bv.z, bv.w};
            #pragma unroll
            for (int i = 0; i < 4; ++i)
                #pragma unroll
                for (int j = 0; j < 4; ++j)
                    acc[i][j] = fmaf(ar[i], br[j], acc[i][j]);
        }
        __syncthreads();
    }

    if (r0 == 0) {
        // q rows (ty<8) / k rows (ty>=8), write transposed [l][c] hi/lo
        float al[4], be[4];
        #pragma unroll
        for (int i = 0; i < 4; ++i) {
            if (ty < 8) {
                int c = ty * 4 + i;
                float sc = qg[c] / sqrtf(qv[c] + EPS_);
                al[i] = sc * QSCL;
                be[i] = (qb[c] * sc + qbe[c] - qm[c] * sc) * QSCL;
            } else {
                int c = (ty - 8) * 4 + i;
                float sc = kg[c] / sqrtf(kvv[c] + EPS_);
                al[i] = sc;
                be[i] = kb[c] * sc + kbe[c] - km[c] * sc;
            }
        }
        short* oh = (ty < 8) ? qT_hi : kT_hi;
        short* ol = (ty < 8) ? qT_lo : kT_lo;
        int cbase = (ty < 8) ? ty * 4 : (ty - 8) * 4;
        #pragma unroll
        for (int j = 0; j < 4; ++j) {
            int lcol = l0 + tx * 4 + j;
            short4v hv, lv;
            #pragma unroll
            for (int i = 0; i < 4; ++i) {
                float v = fmaf(acc[i][j], al[i], be[i]);
                short h = f2bf(v);
                hv[i] = h;
                lv[i] = f2bf(v - bf2f(h));
            }
            size_t off = (size_t)(wi * L + lcol) * 32 + cbase;
            *(short4v*)&oh[off] = hv;
            *(short4v*)&ol[off] = lv;
        }
    } else {
        int vr0 = r0 - 64 + ty * 4;
        #pragma unroll
        for (int i = 0; i < 4; ++i) {
            int vr = vr0 + i;
            float bias = vb[vr];
            short4v hv, lv;
            #pragma unroll
            for (int j = 0; j < 4; ++j) {
                float v = acc[i][j] + bias;
                short h = f2bf(v);
                hv[j] = h;
                lv[j] = f2bf(v - bf2f(h));
            }
            size_t off = (size_t)(wi * 256 + vr) * L + l0 + tx * 4;
            *(short4v*)&v_hi[off] = hv;
            *(short4v*)&v_lo[off] = lv;
        }
    }
}

// ---------------- Kernel 2: MFMA flash attention ----------------
// grid (L/64, Nw), 512 threads (8 waves). Wave w: PV c-range [w*32,w*32+32);
// waves 0-3: scores for keys [w*16,w*16+16).
__global__ __launch_bounds__(512, 2) void attn_kernel(
    const short* __restrict__ qT_hi, const short* __restrict__ qT_lo,
    const short* __restrict__ kT_hi, const short* __restrict__ kT_lo,
    const short* __restrict__ v_hi,  const short* __restrict__ v_lo,
    short* __restrict__ ctx_hi, short* __restrict__ ctx_lo,
    int s, int si)
{
    const int L  = (64 / s) * (64 / s) * 2;
    const int nt = L >> 6;
    const int t  = threadIdx.x;
    const int w  = t >> 6;
    const int l  = t & 63;
    const int wi = blockIdx.y;
    const int q0 = blockIdx.x * 64;
    const int b  = wi % BN_;

    __shared__ short sK[2][4096];     // [buf][plane*2048 + m*32 + c], linear
    __shared__ short sV[32768];       // [plane*16384 + swizzled (c rows of 128B)]
    __shared__ short sP[8192];        // [plane*4096  + swizzled (q rows of 128B)]
    __shared__ float sPmax[4][64], sPsum[4][64];
    __shared__ float sRm[64], sRs[64], sRl[64];
    __shared__ int   sPmap[64];

    if (t < 64) {
        sRm[t] = -1e30f; sRl[t] = 0.f;
        int lq = q0 + t;
        int hs = 64 / s, wsz = 64 / s;
        int i_blk = wi / (s * BN_), j_blk = (wi / BN_) % s;
        int hh = lq / (wsz * 2), rem = lq % (wsz * 2);
        sPmap[t] = (i_blk * hs + hh) * W2_ + (rem & 1) * 64 + j_blk * wsz + (rem >> 1);
    }

    // Q fragments in registers (A-side of scores): q rows, 32 channels
    short8 qh[4], ql[4];
    {
        int c8 = (l >> 4) * 8;
        #pragma unroll
        for (int qt = 0; qt < 4; ++qt) {
            int lq = q0 + qt * 16 + (l & 15);
            size_t off = (size_t)(wi * L + lq) * 32 + c8;
            qh[qt] = *(const short8*)&qT_hi[off];
            ql[qt] = *(const short8*)&qT_lo[off];
        }
    }

    // V staging decode: 8 16B chunks per thread
    const short* gv[8];
    int vlds[8];
    #pragma unroll
    for (int i = 0; i < 8; ++i) {
        int cid = i * 512 + t;
        int plane = cid >> 11, cc = cid & 2047;
        int c = cc >> 3, mq = cc & 7;
        gv[i]  = (plane ? v_lo : v_hi) + (size_t)(wi * 256 + c) * L + mq * 8;
        vlds[i] = plane * 16384 + (swz(c, mq * 16, 128) >> 1);
    }
    // K staging: 1 chunk per thread
    const int kplane = t >> 8, krr = (t >> 2) & 63, kcq = t & 3;
    const short* gk = (kplane ? kT_lo : kT_hi) + (size_t)(wi * L + krr) * 32 + kcq * 8;
    const int klds = kplane * 2048 + krr * 32 + kcq * 8;

    short8 vreg[8], kreg;
    #pragma unroll
    for (int i = 0; i < 8; ++i) vreg[i] = *(const short8*)(gv[i]);
    kreg = *(const short8*)(gk);
    #pragma unroll
    for (int i = 0; i < 8; ++i) *(short8*)&sV[vlds[i]] = vreg[i];
    *(short8*)&sK[0][klds] = kreg;
    __syncthreads();

    f32x4 acc[4][2] = {};
    f32x4 sacc[4];
    int buf = 0;

    #pragma unroll 1
    for (int tt = 0; tt < nt; ++tt) {
        const bool more = (tt + 1 < nt);
        const int m0n = (tt + 1) << 6;
        if (more) kreg = *(const short8*)(gk + (size_t)m0n * 32);

        // ---- scores (waves 0-3)
        if (w < 4) {
            int kidx = (w * 16 + (l & 15)) * 32 + (l >> 4) * 8;
            short8 kbh = *(const short8*)&sK[buf][kidx];
            short8 kbl = *(const short8*)&sK[buf][2048 + kidx];
            #pragma unroll
            for (int qt = 0; qt < 4; ++qt) {
                f32x4 z = {0.f, 0.f, 0.f, 0.f};
                z = mfma16(qh[qt], kbh, z);
                z = mfma16(qh[qt], kbl, z);
                z = mfma16(ql[qt], kbh, z);
                sacc[qt] = z;
            }
            #pragma unroll
            for (int qt = 0; qt < 4; ++qt) {
                float a0 = sacc[qt][0], a1 = sacc[qt][1], a2 = sacc[qt][2], a3 = sacc[qt][3];
                #pragma unroll
                for (int msk = 1; msk <= 8; msk <<= 1) {
                    a0 = fmaxf(a0, __shfl_xor(a0, msk));
                    a1 = fmaxf(a1, __shfl_xor(a1, msk));
                    a2 = fmaxf(a2, __shfl_xor(a2, msk));
                    a3 = fmaxf(a3, __shfl_xor(a3, msk));
                }
                if ((l & 15) == 0) {
                    int qb = qt * 16 + ((l >> 4) << 2);
                    sPmax[w][qb] = a0; sPmax[w][qb + 1] = a1;
                    sPmax[w][qb + 2] = a2; sPmax[w][qb + 3] = a3;
                }
            }
        }
        __syncthreads();                                   // C
        if (t < 64) {
            float mo = sRm[t];
            float pm = fmaxf(fmaxf(sPmax[0][t], sPmax[1][t]),
                             fmaxf(sPmax[2][t], sPmax[3][t]));
            float mn = fmaxf(mo, pm);
            sRm[t] = mn;
            sRs[t] = __expf(mo - mn);
        }
        __syncthreads();                                   // E
        // rescale accumulators
        {
            int qb_ = (l >> 4) << 2;
            #pragma unroll
            for (int qt = 0; qt < 4; ++qt) {
                float r0 = sRs[qt * 16 + qb_ + 0];
                float r1 = sRs[qt * 16 + qb_ + 1];
                float r2 = sRs[qt * 16 + qb_ + 2];
                float r3 = sRs[qt * 16 + qb_ + 3];
                #pragma unroll
                for (int nf = 0; nf < 2; ++nf) {
                    acc[qt][nf][0] *= r0; acc[qt][nf][1] *= r1;
                    acc[qt][nf][2] *= r2; acc[qt][nf][3] *= r3;
                }
            }
        }
        if (w < 4) {
            // P = exp(score - m), write hi/lo to LDS, partial row sums
            int mloc = w * 16 + (l & 15);
            #pragma unroll
            for (int qt = 0; qt < 4; ++qt) {
                int qb = qt * 16 + ((l >> 4) << 2);
                float p0 = __expf(sacc[qt][0] - sRm[qb]);
                float p1 = __expf(sacc[qt][1] - sRm[qb + 1]);
                float p2 = __expf(sacc[qt][2] - sRm[qb + 2]);
                float p3 = __expf(sacc[qt][3] - sRm[qb + 3]);
                float pv[4] = {p0, p1, p2, p3};
                #pragma unroll
                for (int r = 0; r < 4; ++r) {
                    int q = qb + r;
                    int so = swz(q, mloc * 2, 128) >> 1;
                    short h = f2bf(pv[r]);
                    sP[so] = h;
                    sP[4096 + so] = f2bf(pv[r] - bf2f(h));
                }
                float s0 = p0, s1 = p1, s2 = p2, s3 = p3;
                #pragma unroll
                for (int msk = 1; msk <= 8; msk <<= 1) {
                    s0 += __shfl_xor(s0, msk);
                    s1 += __shfl_xor(s1, msk);
                    s2 += __shfl_xor(s2, msk);
                    s3 += __shfl_xor(s3, msk);
                }
                if ((l & 15) == 0) {
                    sPsum[w][qb] = s0; sPsum[w][qb + 1] = s1;
                    sPsum[w][qb + 2] = s2; sPsum[w][qb + 3] = s3;
                }
            }
        }
        __syncthreads();                                   // G
        if (t < 64)
            sRl[t] = sRl[t] * sRs[t] +
                     sPsum[0][t] + sPsum[1][t] + sPsum[2][t] + sPsum[3][t];
        if (more) {
            #pragma unroll
            for (int i = 0; i < 8; ++i) vreg[i] = *(const short8*)(gv[i] + m0n);
            *(short8*)&sK[buf ^ 1][klds] = kreg;           // K(t+1) -> other buffer
        }
        // ---- PV
        #pragma unroll
        for (int kh = 0; kh < 2; ++kh) {
            short8 pah[4], pal[4];
            #pragma unroll
            for (int qt = 0; qt < 4; ++qt) {
                int q = qt * 16 + (l & 15);
                int so = swz(q, kh * 64 + (l >> 4) * 16, 128) >> 1;
                pah[qt] = *(const short8*)&sP[so];
                pal[qt] = *(const short8*)&sP[4096 + so];
            }
            #pragma unroll
            for (int nf = 0; nf < 2; ++nf) {
                int c = w * 32 + nf * 16 + (l & 15);
                int so = swz(c, kh * 64 + (l >> 4) * 16, 128) >> 1;
                short8 vbh = *(const short8*)&sV[so];
                short8 vbl = *(const short8*)&sV[16384 + so];
                #pragma unroll
                for (int qt = 0; qt < 4; ++qt) {
                    acc[qt][nf] = mfma16(pah[qt], vbh, acc[qt][nf]);
                    acc[qt][nf] = mfma16(pah[qt], vbl, acc[qt][nf]);
                    acc[qt][nf] = mfma16(pal[qt], vbh, acc[qt][nf]);
                }
            }
        }
        __syncthreads();                                   // I
        if (more) {
            #pragma unroll
            for (int i = 0; i < 8; ++i) *(short8*)&sV[vlds[i]] = vreg[i];
        }
        buf ^= 1;
    }

    // epilogue: normalize, split hi/lo, scatter to ctx [p][1024]
    #pragma unroll
    for (int qt = 0; qt < 4; ++qt) {
        int qb = qt * 16 + ((l >> 4) << 2);
        float il[4];
        #pragma unroll
        for (int r = 0; r < 4; ++r) il[r] = 1.0f / sRl[qb + r];
        #pragma unroll
        for (int nf = 0; nf < 2; ++nf) {
            int c = si * 256 + w * 32 + nf * 16 + (l & 15);
            #pragma unroll
            for (int r = 0; r < 4; ++r) {
                float v = acc[qt][nf][r] * il[r];
                int p = sPmap[qb + r];
                size_t off = ((size_t)(b * PP + p)) * 1024 + c;
                short h = f2bf(v);
                ctx_hi[off] = h;
                ctx_lo[off] = f2bf(v - bf2f(h));
            }
        }
    }
}

// ---------------- Kernel 3: 3x3 conv via MFMA (9 shifted GEMMs) + BN + ReLU ----------------
// grid (128 [b*64+y], 2 [o-tile]), 512 threads (8 waves: mo=w>>2, np=w&3)
__global__ __launch_bounds__(512, 2) void conv_kernel(
    const short* __restrict__ ctx_hi, const short* __restrict__ ctx_lo,
    const short* __restrict__ wt_hi,  const short* __restrict__ wt_lo,
    const float* __restrict__ cb, const float* __restrict__ cg,
    const float* __restrict__ cbe, const float* __restrict__ cm,
    const float* __restrict__ cv, float* __restrict__ out)
{
    const int t = threadIdx.x, w = t >> 6, l = t & 63;
    const int bimg = blockIdx.x >> 6, y = blockIdx.x & 63;
    const int o0 = blockIdx.y * 128;
    const int mo = w >> 2, np = w & 3;

    __shared__ short sB[24960];       // [plane*12480 + swizzled (390 rows of 64B)]
    __shared__ short sA[2][8192];     // [buf][plane*4096 + swizzled (128 rows of 64B)]
    __shared__ float sAl[128], sBt[128];

    if (t < 128) {
        int o = o0 + t;
        float sc = cg[o] / sqrtf(cv[o] + EPS_);
        sAl[t] = sc;
        sBt[t] = cb[o] * sc + cbe[o] - cm[o] * sc;
    }

    // B-band chunk decode: 2 planes x 390 rows x 4 chunks = 3120, 7 per thread
    const short* gb[7]; int blds[7]; bool bok[7]; bool bval[7];
    #pragma unroll
    for (int i = 0; i < 7; ++i) {
        int cid = i * 512 + t;
        bval[i] = (cid < 3120);
        int cc = bval[i] ? cid : 0;
        int plane = cc / 1560, r2 = cc % 1560;
        int rr = r2 >> 2, cq = r2 & 3;
        int dyi = rr / 130, xx = rr % 130;
        int yy = y + dyi - 1, px = xx - 1;
        bool ok = (yy >= 0 && yy < HH_ && px >= 0 && px < W2_);
        bok[i] = ok;
        size_t p = ok ? ((size_t)bimg * PP + yy * W2_ + px) : 0;
        gb[i] = (plane ? ctx_lo : ctx_hi) + p * 1024 + cq * 8;
        blds[i] = plane * 12480 + (swz(rr, cq * 16, 64) >> 1);
    }
    // A chunk decode: 2 planes x 128 rows x 4 chunks = 1024, 2 per thread
    const short* ga[2]; int alds[2];
    #pragma unroll
    for (int i = 0; i < 2; ++i) {
        int cid = i * 512 + t;
        int plane = cid >> 9, r2 = cid & 511;
        int o = r2 >> 2, cq = r2 & 3;
        ga[i] = (plane ? wt_lo : wt_hi) + (size_t)(o0 + o) * 1024 + cq * 8;
        alds[i] = plane * 4096 + (swz(o, cq * 16, 64) >> 1);
    }

    f32x4 acc[4][2] = {};
    const short8 z8 = {};

    #pragma unroll 1
    for (int c0 = 0; c0 < 1024; c0 += 32) {
        // stage B band (all 9 taps reuse it) + A for d=0
        #pragma unroll
        for (int i = 0; i < 7; ++i) {
            if (bval[i]) {
                short8 v = bok[i] ? *(const short8*)(gb[i] + c0) : z8;
                *(short8*)&sB[blds[i]] = v;
            }
        }
        #pragma unroll
        for (int i = 0; i < 2; ++i) {
            short8 v = *(const short8*)(ga[i] + c0);
            *(short8*)&sA[0][alds[i]] = v;
        }
        __syncthreads();
        #pragma unroll
        for (int d = 0; d < 9; ++d) {
            if (d < 8) {
                #pragma unroll
                for (int i = 0; i < 2; ++i) {
                    short8 v = *(const short8*)(ga[i] + (size_t)(d + 1) * 262144 + c0);
                    *(short8*)&sA[(d + 1) & 1][alds[i]] = v;
                }
            }
            const int ky = d / 3, kx = d % 3;
            short8 ah[4], al[4];
            #pragma unroll
            for (int mf = 0; mf < 4; ++mf) {
                int ro = mo * 64 + mf * 16 + (l & 15);
                int so = swz(ro, (l >> 4) * 16, 64) >> 1;
                ah[mf] = *(const short8*)&sA[d & 1][so];
                al[mf] = *(const short8*)&sA[d & 1][4096 + so];
            }
            short8 bh[2], bl2[2];
            #pragma unroll
            for (int nf = 0; nf < 2; ++nf) {
                int rb = ky * 130 + np * 32 + nf * 16 + (l & 15) + kx;
                int so = swz(rb, (l >> 4) * 16, 64) >> 1;
                bh[nf]  = *(const short8*)&sB[so];
                bl2[nf] = *(const short8*)&sB[12480 + so];
            }
            #pragma unroll
            for (int mf = 0; mf < 4; ++mf)
                #pragma unroll
                for (int nf = 0; nf < 2; ++nf) {
                    acc[mf][nf] = mfma16(ah[mf], bh[nf],  acc[mf][nf]);
                    acc[mf][nf] = mfma16(ah[mf], bl2[nf], acc[mf][nf]);
                    acc[mf][nf] = mfma16(al[mf], bh[nf],  acc[mf][nf]);
                }
            __syncthreads();
        }
    }

    // epilogue: BN + ReLU + fp32 store
    #pragma unroll
    for (int mf = 0; mf < 4; ++mf) {
        #pragma unroll
        for (int r = 0; r < 4; ++r) {
            int ol = mo * 64 + mf * 16 + ((l >> 4) << 2) + r;
            float a = sAl[ol], bt = sBt[ol];
            #pragma unroll
            for (int nf = 0; nf < 2; ++nf) {
                int x = np * 32 + nf * 16 + (l & 15);
                float v = fmaxf(fmaf(acc[mf][nf][r], a, bt), 0.f);
                out[((size_t)(bimg * 256 + o0 + ol)) * PP + y * W2_ + x] = v;
            }
        }
    }
}

// ---------------- host launch ----------------
extern "C" void kernel_launch(void* const* d_in, const int* in_sizes, int n_in,
                              void* d_out, int out_size, void* d_ws, size_t ws_size,
                              hipStream_t stream)
{
    const float* feats  = (const float*)d_in[0];
    const float* q_w    = (const float*)d_in[1];
    const float* q_b    = (const float*)d_in[2];
    const float* q_g    = (const float*)d_in[3];
    const float* q_be   = (const float*)d_in[4];
    const float* q_m    = (const float*)d_in[5];
    const float* q_v    = (const float*)d_in[6];
    const float* k_w    = (const float*)d_in[7];
    const float* k_b    = (const float*)d_in[8];
    const float* k_g    = (const float*)d_in[9];
    const float* k_be   = (const float*)d_in[10];
    const float* k_m    = (const float*)d_in[11];
    const float* k_v    = (const float*)d_in[12];
    const float* v_w    = (const float*)d_in[13];
    const float* v_b    = (const float*)d_in[14];
    const float* conv_w = (const float*)d_in[15];
    const float* conv_b = (const float*)d_in[16];
    const float* c_g    = (const float*)d_in[17];
    const float* c_be   = (const float*)d_in[18];
    const float* c_m    = (const float*)d_in[19];
    const float* c_v    = (const float*)d_in[20];

    short* ws     = (short*)d_ws;
    short* ctx_hi = ws;                  // 16,777,216 shorts
    short* ctx_lo = ws + 16777216;       // 16,777,216
    short* v_hi   = ws + 33554432;       //  4,194,304
    short* v_lo   = ws + 37748736;       //  4,194,304
    short* qT_hi  = ws + 41943040;       //    524,288
    short* qT_lo  = ws + 42467328;       //    524,288
    short* kT_hi  = ws + 42991616;       //    524,288
    short* kT_lo  = ws + 43515904;       //    524,288
    short* wt_hi  = ws + 44040192;       //  2,359,296
    short* wt_lo  = ws + 46399488;       //  2,359,296
    // total 48,758,784 shorts = 97,517,568 B (== round-0 footprint)

    wsplit_kernel<<<dim3(256, 4), dim3(256), 0, stream>>>(conv_w, wt_hi, wt_lo);

    const int sizes[4] = {1, 2, 4, 8};
    for (int si = 0; si < 4; ++si) {
        int s = sizes[si];
        int L = (64 / s) * (64 / s) * 2;
        int Nw = s * s * BN_;
        qkv_kernel<<<dim3(256, 5), dim3(256), 0, stream>>>(
            feats,
            q_w + si * 32 * 256, q_b + si * 32, q_g + si * 32, q_be + si * 32,
            q_m + si * 32, q_v + si * 32,
            k_w + si * 32 * 256, k_b + si * 32, k_g + si * 32, k_be + si * 32,
            k_m + si * 32, k_v + si * 32,
            v_w + si * 256 * 256, v_b + si * 256,
            qT_hi, qT_lo, kT_hi, kT_lo, v_hi, v_lo, s);
        attn_kernel<<<dim3(L / 64, Nw), dim3(512), 0, stream>>>(
            qT_hi, qT_lo, kT_hi, kT_lo, v_hi, v_lo, ctx_hi, ctx_lo, s, si);
    }

    conv_kernel<<<dim3(128, 2), dim3(512), 0, stream>>>(
        ctx_hi, ctx_lo, wt_hi, wt_lo, conv_b, c_g, c_be, c_m, c_v, (float*)d_out);
}